// Round 15
// baseline (119.277 us; speedup 1.0000x reference)
//
#include <hip/hip_runtime.h>
#include <hip/hip_bf16.h>

// MultiheadSelfAttention: x(2,2048,1024) f32 -> QKV proj + RoPE -> causal attn -> out proj
// Round 15: Q/K stored in natural GEMM layout [b*s][e] (coalesced epilogue, no scatter
//           decode); attn reads Q/K at row-stride DM. V keeps [b,h,d,s]. Else as R14.

#define BATCH 2
#define SEQ   2048
#define NH    16
#define HD    64
#define DM    1024
#define MTOT  (BATCH*SEQ)   // 4096

typedef __attribute__((ext_vector_type(8))) short bf16x8;
typedef __attribute__((ext_vector_type(4))) float f32x4;
typedef __attribute__((ext_vector_type(4))) unsigned int u32x4;
typedef unsigned short u16;
typedef unsigned int   u32;

__device__ __forceinline__ float b2f(u16 h){ return __uint_as_float(((u32)h) << 16); }
__device__ __forceinline__ u16 f2b(float f){
  u32 u = __float_as_uint(f);
  u32 r = (u + 0x7FFFu + ((u >> 16) & 1u)) >> 16;   // RNE
  return (u16)r;
}
// compiler-scheduled f32->bf16 (m240: don't hand-write cvt_pk)
__device__ __forceinline__ u16 cvt1(float f){
  __hip_bfloat16 h = __float2bfloat16(f);
  return *reinterpret_cast<u16*>(&h);
}
__device__ __forceinline__ u32 pk2(float lo, float hi){
  return (u32)cvt1(lo) | ((u32)cvt1(hi) << 16);
}
__device__ __forceinline__ f32x4 mfma16(bf16x8 a, bf16x8 b, f32x4 c){
  return __builtin_amdgcn_mfma_f32_16x16x32_bf16(a, b, c, 0, 0, 0);
}
__device__ __forceinline__ void gload_lds16(const u16* g, u16* l){
  __builtin_amdgcn_global_load_lds((const __attribute__((address_space(1))) unsigned int*)g,
                                   (__attribute__((address_space(3))) unsigned int*)l, 16, 0, 0);
}

// ---------------- fp32 -> bf16 conversion for x and the 4 weights ----------------
__global__ __launch_bounds__(256) void cvt_all(const float* __restrict__ x,
    const float* __restrict__ wq, const float* __restrict__ wk,
    const float* __restrict__ wv, const float* __restrict__ wo,
    u16* __restrict__ xb, u16* __restrict__ wb)
{
  const long NX = (long)MTOT * DM;       // 4194304
  const long NW = (long)DM * DM;         // 1048576
  const long tot4 = (NX + 4*NW) >> 2;
  for (long t = (long)blockIdx.x*blockDim.x + threadIdx.x; t < tot4;
       t += (long)gridDim.x*blockDim.x){
    long e = t << 2;
    const float* s; u16* d;
    if (e < NX){ s = x + e; d = xb + e; }
    else {
      long j = e - NX; int z = (int)(j >> 20);
      const float* ws = (z==0)?wq:(z==1)?wk:(z==2)?wv:wo;
      s = ws + (j & (NW-1)); d = wb + j;
    }
    float4 v = *(const float4*)s;
    u32 lo = (u32)f2b(v.x) | ((u32)f2b(v.y) << 16);
    u32 hi = (u32)f2b(v.z) | ((u32)f2b(v.w) << 16);
    uint2 o; o.x = lo; o.y = hi;
    *(uint2*)d = o;
  }
}

// ---------------- RoPE cos/sin table: [SEQ][32] float2 ----------------
__global__ __launch_bounds__(256) void rope_table(float2* __restrict__ tab){
  int t = blockIdx.x*blockDim.x + threadIdx.x;
  if (t >= SEQ*32) return;
  int s = t >> 5, i = t & 31;
  float inv = 1.0f / powf(10000.0f, (float)i * (1.0f/32.0f));
  float a = (float)s * inv;
  tab[t] = make_float2(cosf(a), sinf(a));
}

// ---------------- gemm_qkv: 128x128 tile + fused RoPE epilogue --------------------
// 1D grid 768, XCD-swizzled. z=0: Q -> rope*SC -> Qd[b*s][e] (natural layout);
// z=1: K -> rope -> Kd[b*s][e]; z=2: V -> transposed Vt[b,h,d,s].
__global__ __launch_bounds__(256) void gemm_qkv(const u16* __restrict__ xb,
                                                const u16* __restrict__ wb,
                                                u16* __restrict__ Qd, u16* __restrict__ Kd,
                                                u16* __restrict__ Vt,
                                                const float2* __restrict__ tab,
                                                const int* __restrict__ pos)
{
  __shared__ u16 Alds[128*64];
  __shared__ u16 Blds[128*64];
  const int fid = blockIdx.x;
  const int xj = fid & 7, tt = fid >> 3;          // xcd, 0..95
  const int mb = (tt/24)*8 + xj;                  // 0..31
  const int rest = tt % 24;
  const int nb = rest & 7, z = rest >> 3;         // 0..7, 0..2
  const u16* Bm = wb + (long)z * DM * DM;
  const int nbase = nb*128, mbase = mb*128;
  const int tid = threadIdx.x;
  const int w = tid >> 6, l = tid & 63, g = l >> 4, c = l & 15;
  const int wr = (w >> 1)*64, wc = (w & 1)*64;
  const int srow = l >> 3;
  const int scol = ((l & 7) ^ srow)*8;
  const u16* Ag = xb + (long)(mbase + w*32 + srow)*DM + scol;
  const u16* Bg = Bm + (long)(nbase + w*32 + srow)*DM + scol;
  u16* Alb = Alds + w*2048;
  u16* Blb = Blds + w*2048;
  f32x4 acc[4][4] = {};

  for (int k0 = 0; k0 < DM; k0 += 64){
    __syncthreads();
    #pragma unroll
    for (int i = 0; i < 4; i++){
      gload_lds16(Ag + k0 + (long)(8*i)*DM, Alb + i*512);
      gload_lds16(Bg + k0 + (long)(8*i)*DM, Blb + i*512);
    }
    __syncthreads();
    #pragma unroll
    for (int ks = 0; ks < 2; ks++){
      bf16x8 af[4], bfr[4];
      #pragma unroll
      for (int mi = 0; mi < 4; mi++){
        int row = wr + mi*16 + c;
        af[mi] = *(const bf16x8*)&Alds[row*64 + (((ks*4 + g) ^ (row & 7))*8)];
      }
      #pragma unroll
      for (int nj = 0; nj < 4; nj++){
        int row = wc + nj*16 + c;
        bfr[nj] = *(const bf16x8*)&Blds[row*64 + (((ks*4 + g) ^ (row & 7))*8)];
      }
      #pragma unroll
      for (int mi = 0; mi < 4; mi++)
        #pragma unroll
        for (int nj = 0; nj < 4; nj++)
          acc[mi][nj] = mfma16(af[mi], bfr[nj], acc[mi][nj]);
    }
  }

  if (z == 2){
    // V: transposed write, rows 4g+r consecutive -> ushort4 stores
    #pragma unroll
    for (int mi = 0; mi < 4; mi++){
      int row0 = mbase + wr + mi*16 + 4*g;
      int bb = row0 >> 11, s0 = row0 & (SEQ-1);
      #pragma unroll
      for (int nj = 0; nj < 4; nj++){
        int col = nbase + wc + nj*16 + c;
        int hh = col >> 6, d = col & 63;
        ushort4 v;
        v.x = cvt1(acc[mi][nj][0]); v.y = cvt1(acc[mi][nj][1]);
        v.z = cvt1(acc[mi][nj][2]); v.w = cvt1(acc[mi][nj][3]);
        *(ushort4*)&Vt[((long)(bb*NH + hh)*HD + d)*SEQ + s0] = v;
      }
    }
  } else {
    u16* Out = (z == 0) ? Qd : Kd;
    const float scale = (z == 0) ? 0.125f*1.44269504089f : 1.f;  // SC folded into Q
    const bool even = (c & 1) == 0;
    #pragma unroll
    for (int mi = 0; mi < 4; mi++){
      #pragma unroll
      for (int r = 0; r < 4; r++){
        int row = mbase + wr + mi*16 + 4*g + r;
        int bb = row >> 11, s = row & (SEQ-1);
        int p = pos[bb*SEQ + s];
        if (p < 0) p = 0; if (p >= SEQ) p = SEQ - 1;
        #pragma unroll
        for (int nj = 0; nj < 4; nj++){
          int col = nbase + wc + nj*16 + c;
          float2 cs = tab[p*32 + ((col & 63) >> 1)];
          float own = acc[mi][nj][r];
          float prt = __shfl_xor(own, 1);
          float rr = even ? (own*cs.x - prt*cs.y) : (prt*cs.y + own*cs.x);
          rr *= scale;
          Out[(long)row*DM + col] = cvt1(rr);   // natural layout, coalesced
        }
      }
    }
  }
}

// ---------------- gemm_out: 128x64 tile, 1D grid 512 XCD-swizzled ----------------
__global__ __launch_bounds__(256) void gemm_out(const u16* __restrict__ Zb,
                                                const u16* __restrict__ wob,
                                                float* __restrict__ out)
{
  __shared__ u16 Alds[128*64];
  __shared__ u16 Blds[64*64];
  const int fid = blockIdx.x;
  const int xj = fid & 7, tt = fid >> 3;          // 0..63
  const int mb = (tt/16)*8 + xj;                  // 0..31
  const int nb = tt % 16;                         // 0..15
  const int nbase = nb*64, mbase = mb*128;
  const int tid = threadIdx.x;
  const int w = tid >> 6, l = tid & 63, g = l >> 4, c = l & 15;
  const int wr = (w >> 1)*64, wc = (w & 1)*32;
  const int srow = l >> 3;
  const int scol = ((l & 7) ^ srow)*8;
  const u16* Ag = Zb  + (long)(mbase + w*32 + srow)*DM + scol;
  const u16* Bg = wob + (long)(nbase + w*16 + srow)*DM + scol;
  u16* Alb = Alds + w*2048;
  u16* Blb = Blds + w*1024;
  f32x4 acc[4][2] = {};

  for (int k0 = 0; k0 < DM; k0 += 64){
    __syncthreads();
    #pragma unroll
    for (int i = 0; i < 4; i++)
      gload_lds16(Ag + k0 + (long)(8*i)*DM, Alb + i*512);
    #pragma unroll
    for (int i = 0; i < 2; i++)
      gload_lds16(Bg + k0 + (long)(8*i)*DM, Blb + i*512);
    __syncthreads();
    #pragma unroll
    for (int ks = 0; ks < 2; ks++){
      bf16x8 af[4], bfr[2];
      #pragma unroll
      for (int mi = 0; mi < 4; mi++){
        int row = wr + mi*16 + c;
        af[mi] = *(const bf16x8*)&Alds[row*64 + (((ks*4 + g) ^ (row & 7))*8)];
      }
      #pragma unroll
      for (int nj = 0; nj < 2; nj++){
        int row = wc + nj*16 + c;
        bfr[nj] = *(const bf16x8*)&Blds[row*64 + (((ks*4 + g) ^ (row & 7))*8)];
      }
      #pragma unroll
      for (int mi = 0; mi < 4; mi++)
        #pragma unroll
        for (int nj = 0; nj < 2; nj++)
          acc[mi][nj] = mfma16(af[mi], bfr[nj], acc[mi][nj]);
    }
  }
  #pragma unroll
  for (int mi = 0; mi < 4; mi++)
    #pragma unroll
    for (int nj = 0; nj < 2; nj++)
      #pragma unroll
      for (int r = 0; r < 4; r++){
        int row = mbase + wr + mi*16 + 4*g + r;
        int col = nbase + wc + nj*16 + c;
        out[(long)row*DM + col] = acc[mi][nj][r];
      }
}

// ---------------- causal flash attention: paired qtiles x KV-split ----------
// Q/K read from natural layout [b*s][e] (row stride DM, h-slice columns).
// 1D grid 1024, XCD-swizzled. R11 math, R12 addressing.
__device__ __forceinline__ int kperm(int a){
  return (a & 32) | ((a & 4) << 2) | ((a & 24) >> 1) | (a & 3);
}

__global__ __launch_bounds__(256) void attn(const u16* __restrict__ Q, const u16* __restrict__ K,
                                            const u16* __restrict__ Vt,
                                            u16* __restrict__ Opart, float* __restrict__ Lsum)
{
  const int fid = blockIdx.x;
  const int xj = fid & 7, tt = fid >> 3;          // 0..127
  const int grp = (tt >> 5)*8 + xj;               // 0..31  (h,b) group
  const int within = tt & 31;                     // 0..31
  const int h = grp & 15, b = grp >> 4;
  const int pair = within >> 1;
  const int half = within & 1;
  const int tid = threadIdx.x, w = tid >> 6, l = tid & 63, g = l >> 4, c = l & 15;
  const u16* Kp = K  + (long)(b*SEQ)*DM + h*HD;    // row stride DM
  const u16* Vp = Vt + (long)(b*NH + h)*HD*SEQ;

  __shared__ u16 KV[2][2][64][64];   // [buf][0=K,1=V][row][col]
  u16* kv = &KV[0][0][0][0];

  const int srow0 = tid >> 3, sch = tid & 7;
  const int kpr0 = kperm(srow0), kpr1 = kperm(srow0 + 32);
  const int cswz = c & 7;

  // loop-invariant LDS offsets (elements)
  const int wk0 = kpr0*64 + (sch ^ (kpr0 & 7))*8;
  const int wk1 = kpr1*64 + (sch ^ (kpr1 & 7))*8;
  const int wv0 = 4096 + srow0*64 + (sch ^ (srow0 & 7))*8;
  const int wv1 = 4096 + (srow0 + 32)*64 + (sch ^ ((srow0 + 32) & 7))*8;
  const int ra0 = c*64 + (((0 + g) ^ cswz)*8);
  const int ra1 = c*64 + (((4 + g) ^ cswz)*8);

  bf16x8 ones;
  #pragma unroll
  for (int j = 0; j < 8; j++) ones[j] = (short)0x3F80;   // bf16 1.0

  int bufo = 0;                      // element offset of current buffer (0 / 8192)
  #pragma unroll 1
  for (int seg = 0; seg < 2; ++seg){
    const int qt = seg ? (31 - pair) : pair;
    const int qbase = qt*64;
    const int qrow = qbase + w*16;
    const u16* Qp = Q + (long)(b*SEQ + qrow)*DM + h*HD;   // row stride DM
    bf16x8 qf0 = *(const bf16x8*)(Qp + c*DM + g*8);
    bf16x8 qf1 = *(const bf16x8*)(Qp + c*DM + 32 + g*8);

    const int ntH0  = (qt + 2) >> 1;            // ceil((qt+1)/2)
    const int tstart = half ? ntH0 : 0;
    const int tend   = half ? (qt + 1) : ntH0;

    f32x4 accz[4] = {};
    f32x4 lacc = {};                            // row-sums, acc layout (q=4g+r)

    if (tstart < tend){
      __syncthreads();   // previous segment's LDS reads complete
      const u16* kg0 = Kp + (long)(tstart*64 + srow0)*DM + sch*8;
      const u16* kg1 = kg0 + (long)32*DM;
      const u16* vg0 = Vp + (long)srow0*SEQ + tstart*64 + sch*8;
      const u16* vg1 = vg0 + 32*SEQ;
      bf16x8 kr0 = *(const bf16x8*)kg0, kr1 = *(const bf16x8*)kg1;
      bf16x8 vr0 = *(const bf16x8*)vg0, vr1 = *(const bf16x8*)vg1;
      kg0 += (long)64*DM; kg1 += (long)64*DM; vg0 += 64; vg1 += 64;
      *(bf16x8*)(kv + bufo + wk0) = kr0;
      *(bf16x8*)(kv + bufo + wk1) = kr1;
      *(bf16x8*)(kv + bufo + wv0) = vr0;
      *(bf16x8*)(kv + bufo + wv1) = vr1;

      for (int t = tstart; t < tend; ++t){
        const int kbase = t*64;
        __syncthreads();   // buf ready; all prior reads of other buf done

        if (t < tend-1){   // T14: issue next tile's global loads now, write LDS later
          kr0 = *(const bf16x8*)kg0; kr1 = *(const bf16x8*)kg1;
          vr0 = *(const bf16x8*)vg0; vr1 = *(const bf16x8*)vg1;
          kg0 += (long)64*DM; kg1 += (long)64*DM; vg0 += 64; vg1 += 64;
        }

        const u16* kvb = kv + bufo;

        // QK^T (swapped): s[sub][r] = S_stored[sub*16+4g+r][q=c], pre-scaled
        f32x4 s[4];
        __builtin_amdgcn_s_setprio(1);
        #pragma unroll
        for (int sub = 0; sub < 4; sub++){
          bf16x8 ka0 = *(const bf16x8*)(kvb + ra0 + sub*1024);
          bf16x8 ka1 = *(const bf16x8*)(kvb + ra1 + sub*1024);
          f32x4 z4 = {};
          z4 = mfma16(ka0, qf0, z4);
          z4 = mfma16(ka1, qf1, z4);
          s[sub] = z4;
        }
        __builtin_amdgcn_s_setprio(0);

        // causal mask; then P = exp2(s) directly (drop-max: inputs bounded)
        const bool edge = (kbase + 63 > qrow);
        const int q = qrow + c;
        if (edge){
          #pragma unroll
          for (int sub = 0; sub < 4; sub++)
            #pragma unroll
            for (int r = 0; r < 4; r++){
              int key = kbase + ((sub >> 1) << 5) + 8*g + ((sub & 1) << 2) + r;
              if (key > q) s[sub][r] = -1e30f;
            }
        }
        #pragma unroll
        for (int sub = 0; sub < 4; sub++)
          #pragma unroll
          for (int r = 0; r < 4; r++)
            s[sub][r] = exp2f(s[sub][r]);

        // P -> bf16 A-frags, fully in-lane (keys 8g..8g+7 and 32+8g..+7)
        u32x4 p0, p1;
        p0[0] = pk2(s[0][0], s[0][1]); p0[1] = pk2(s[0][2], s[0][3]);
        p0[2] = pk2(s[1][0], s[1][1]); p0[3] = pk2(s[1][2], s[1][3]);
        p1[0] = pk2(s[2][0], s[2][1]); p1[1] = pk2(s[2][2], s[2][3]);
        p1[2] = pk2(s[3][0], s[3][1]); p1[3] = pk2(s[3][2], s[3][3]);
        bf16x8 pf0 = __builtin_bit_cast(bf16x8, p0);
        bf16x8 pf1 = __builtin_bit_cast(bf16x8, p1);

        // PV + row-sum (ones-MFMA): lacc[r] += sum_k P[q=4g+r][k]
        __builtin_amdgcn_s_setprio(1);
        lacc = mfma16(pf0, ones, lacc);
        lacc = mfma16(pf1, ones, lacc);
        #pragma unroll
        for (int dt = 0; dt < 4; dt++){
          bf16x8 vf0 = *(const bf16x8*)(kvb + 4096 + ra0 + dt*1024);
          bf16x8 vf1 = *(const bf16x8*)(kvb + 4096 + ra1 + dt*1024);
          accz[dt] = mfma16(pf0, vf0, accz[dt]);
          accz[dt] = mfma16(pf1, vf1, accz[dt]);
        }
        __builtin_amdgcn_s_setprio(0);

        if (t < tend-1){   // write next tile into the other buffer (no barrier needed)
          int nbo = bufo ^ 8192;
          *(bf16x8*)(kv + nbo + wk0) = kr0;
          *(bf16x8*)(kv + nbo + wk1) = kr1;
          *(bf16x8*)(kv + nbo + wv0) = vr0;
          *(bf16x8*)(kv + nbo + wv1) = vr1;
          bufo = nbo;
        }
      }
    }

    // write partials: unnormalized O (bf16) + lsum per row (q = 4g+r)
    const int pbase = (((b*NH + h)*32 + qt)*2 + half);
    if (c == 0){
      #pragma unroll
      for (int r = 0; r < 4; r++)
        Lsum[pbase*64 + w*16 + 4*g + r] = lacc[r];
    }
    u16* Op = Opart + (long)pbase*(64*64);
    #pragma unroll
    for (int dt = 0; dt < 4; dt++)
      #pragma unroll
      for (int r = 0; r < 4; r++)
        Op[(w*16 + 4*g + r)*64 + dt*16 + c] = cvt1(accz[dt][r]);
  }
}

// ---------------- combine the two KV-halves (no max shift needed) ----------
__global__ __launch_bounds__(256) void attn_combine(const u16* __restrict__ Opart,
                                                    const float* __restrict__ Lsum,
                                                    u16* __restrict__ Z)
{
  const int qt = blockIdx.x, h = blockIdx.y, b = blockIdx.z;   // qt 0..31
  const int p0 = ((b*NH + h)*32 + qt)*2, p1 = p0 + 1;
  const int row = threadIdx.x >> 2;          // 0..63
  const int d0  = (threadIdx.x & 3)*16;
  float inv = 1.f / (Lsum[p0*64 + row] + Lsum[p1*64 + row]);
  const u16* o0 = Opart + ((long)p0*64 + row)*64 + d0;
  const u16* o1 = Opart + ((long)p1*64 + row)*64 + d0;
  const int s = qt*64 + row;
  u16* zp = Z + (long)(b*SEQ + s)*DM + h*HD + d0;
  #pragma unroll
  for (int j = 0; j < 2; j++){
    bf16x8 va = *(const bf16x8*)(o0 + j*8);
    bf16x8 vb = *(const bf16x8*)(o1 + j*8);
    bf16x8 ov;
    #pragma unroll
    for (int e = 0; e < 8; e++){
      float z = (b2f((u16)va[e]) + b2f((u16)vb[e]))*inv;
      ov[e] = (short)cvt1(z);
    }
    *(bf16x8*)(zp + j*8) = ov;
  }
}

extern "C" void kernel_launch(void* const* d_in, const int* in_sizes, int n_in,
                              void* d_out, int out_size, void* d_ws, size_t ws_size,
                              hipStream_t stream)
{
  const float* x  = (const float*)d_in[0];
  const int*   pos= (const int*)d_in[1];
  const float* wq = (const float*)d_in[2];
  const float* wk = (const float*)d_in[3];
  const float* wv = (const float*)d_in[4];
  const float* wo = (const float*)d_in[5];
  float* out = (float*)d_out;

  const long NX = (long)MTOT*DM;
  const long NW = (long)DM*DM;
  char* p = (char*)d_ws;
  u16* xb   = (u16*)p;  p += NX*2;
  u16* wb   = (u16*)p;  p += 4*NW*2;
  u16* Qd   = (u16*)p;  p += NX*2;
  u16* Kd   = (u16*)p;  p += NX*2;
  u16* Vt   = (u16*)p;  p += NX*2;
  u16* Zb   = (u16*)p;  p += NX*2;
  float2* tab = (float2*)p; p += (long)SEQ*32*sizeof(float2);
  u16* Opart = (u16*)p;  p += 2L*NX*2;                 // 2048 chunks x 64x64 bf16
  float* Lsum = (float*)p; p += 2048L*64*sizeof(float);
  (void)ws_size; (void)n_in; (void)in_sizes; (void)out_size;

  hipLaunchKernelGGL(cvt_all,     dim3(2048),      dim3(256), 0, stream, x, wq, wk, wv, wo, xb, wb);
  hipLaunchKernelGGL(rope_table,  dim3(256),       dim3(256), 0, stream, tab);
  hipLaunchKernelGGL(gemm_qkv,    dim3(768),       dim3(256), 0, stream, xb, wb, Qd, Kd, Vt, tab, pos);
  hipLaunchKernelGGL(attn,        dim3(1024),      dim3(256), 0, stream, Qd, Kd, Vt, Opart, Lsum);
  hipLaunchKernelGGL(attn_combine,dim3(32,16,2),   dim3(256), 0, stream, Opart, Lsum, Zb);
  hipLaunchKernelGGL(gemm_out,    dim3(512),       dim3(256), 0, stream, Zb, wb + 3*NW, out);
}

// Round 16
// 116.668 us; speedup vs baseline: 1.0224x; 1.0224x over previous
//
#include <hip/hip_runtime.h>
#include <hip/hip_bf16.h>

// MultiheadSelfAttention: x(2,2048,1024) f32 -> QKV proj + RoPE -> causal attn -> out proj
// Round 16: gemm_qkv re-tiled 128x64 (1536 blocks, 6/CU) matching gemm_out's measured
//           860 TF structure; RoPE epilogue carried over. Else byte-identical to R15.

#define BATCH 2
#define SEQ   2048
#define NH    16
#define HD    64
#define DM    1024
#define MTOT  (BATCH*SEQ)   // 4096

typedef __attribute__((ext_vector_type(8))) short bf16x8;
typedef __attribute__((ext_vector_type(4))) float f32x4;
typedef __attribute__((ext_vector_type(4))) unsigned int u32x4;
typedef unsigned short u16;
typedef unsigned int   u32;

__device__ __forceinline__ float b2f(u16 h){ return __uint_as_float(((u32)h) << 16); }
__device__ __forceinline__ u16 f2b(float f){
  u32 u = __float_as_uint(f);
  u32 r = (u + 0x7FFFu + ((u >> 16) & 1u)) >> 16;   // RNE
  return (u16)r;
}
// compiler-scheduled f32->bf16 (m240: don't hand-write cvt_pk)
__device__ __forceinline__ u16 cvt1(float f){
  __hip_bfloat16 h = __float2bfloat16(f);
  return *reinterpret_cast<u16*>(&h);
}
__device__ __forceinline__ u32 pk2(float lo, float hi){
  return (u32)cvt1(lo) | ((u32)cvt1(hi) << 16);
}
__device__ __forceinline__ f32x4 mfma16(bf16x8 a, bf16x8 b, f32x4 c){
  return __builtin_amdgcn_mfma_f32_16x16x32_bf16(a, b, c, 0, 0, 0);
}
__device__ __forceinline__ void gload_lds16(const u16* g, u16* l){
  __builtin_amdgcn_global_load_lds((const __attribute__((address_space(1))) unsigned int*)g,
                                   (__attribute__((address_space(3))) unsigned int*)l, 16, 0, 0);
}

// ---------------- fp32 -> bf16 conversion for x and the 4 weights ----------------
__global__ __launch_bounds__(256) void cvt_all(const float* __restrict__ x,
    const float* __restrict__ wq, const float* __restrict__ wk,
    const float* __restrict__ wv, const float* __restrict__ wo,
    u16* __restrict__ xb, u16* __restrict__ wb)
{
  const long NX = (long)MTOT * DM;       // 4194304
  const long NW = (long)DM * DM;         // 1048576
  const long tot4 = (NX + 4*NW) >> 2;
  for (long t = (long)blockIdx.x*blockDim.x + threadIdx.x; t < tot4;
       t += (long)gridDim.x*blockDim.x){
    long e = t << 2;
    const float* s; u16* d;
    if (e < NX){ s = x + e; d = xb + e; }
    else {
      long j = e - NX; int z = (int)(j >> 20);
      const float* ws = (z==0)?wq:(z==1)?wk:(z==2)?wv:wo;
      s = ws + (j & (NW-1)); d = wb + j;
    }
    float4 v = *(const float4*)s;
    u32 lo = (u32)f2b(v.x) | ((u32)f2b(v.y) << 16);
    u32 hi = (u32)f2b(v.z) | ((u32)f2b(v.w) << 16);
    uint2 o; o.x = lo; o.y = hi;
    *(uint2*)d = o;
  }
}

// ---------------- RoPE cos/sin table: [SEQ][32] float2 ----------------
__global__ __launch_bounds__(256) void rope_table(float2* __restrict__ tab){
  int t = blockIdx.x*blockDim.x + threadIdx.x;
  if (t >= SEQ*32) return;
  int s = t >> 5, i = t & 31;
  float inv = 1.0f / powf(10000.0f, (float)i * (1.0f/32.0f));
  float a = (float)s * inv;
  tab[t] = make_float2(cosf(a), sinf(a));
}

// ---------------- gemm_qkv: 128x64 tile + fused RoPE epilogue --------------------
// 1D grid 1536, XCD-swizzled: mb = (tt/48)*8+xj, rest = tt%48 -> nb 0..15, z 0..2.
// z=0: Q -> rope*SC -> Qd[b*s][e]; z=1: K -> rope -> Kd[b*s][e]; z=2: V -> Vt[b,h,d,s].
__global__ __launch_bounds__(256) void gemm_qkv(const u16* __restrict__ xb,
                                                const u16* __restrict__ wb,
                                                u16* __restrict__ Qd, u16* __restrict__ Kd,
                                                u16* __restrict__ Vt,
                                                const float2* __restrict__ tab,
                                                const int* __restrict__ pos)
{
  __shared__ u16 Alds[128*64];
  __shared__ u16 Blds[64*64];
  const int fid = blockIdx.x;
  const int xj = fid & 7, tt = fid >> 3;          // xcd, 0..191
  const int mb = (tt/48)*8 + xj;                  // 0..31
  const int rest = tt % 48;
  const int nb = rest & 15, z = rest >> 4;        // 0..15, 0..2
  const u16* Bm = wb + (long)z * DM * DM;
  const int nbase = nb*64, mbase = mb*128;
  const int tid = threadIdx.x;
  const int w = tid >> 6, l = tid & 63, g = l >> 4, c = l & 15;
  const int wr = (w >> 1)*64, wc = (w & 1)*32;
  const int srow = l >> 3;
  const int scol = ((l & 7) ^ srow)*8;
  const u16* Ag = xb + (long)(mbase + w*32 + srow)*DM + scol;
  const u16* Bg = Bm + (long)(nbase + w*16 + srow)*DM + scol;
  u16* Alb = Alds + w*2048;
  u16* Blb = Blds + w*1024;
  f32x4 acc[4][2] = {};

  for (int k0 = 0; k0 < DM; k0 += 64){
    __syncthreads();
    #pragma unroll
    for (int i = 0; i < 4; i++)
      gload_lds16(Ag + k0 + (long)(8*i)*DM, Alb + i*512);
    #pragma unroll
    for (int i = 0; i < 2; i++)
      gload_lds16(Bg + k0 + (long)(8*i)*DM, Blb + i*512);
    __syncthreads();
    #pragma unroll
    for (int ks = 0; ks < 2; ks++){
      bf16x8 af[4], bfr[2];
      #pragma unroll
      for (int mi = 0; mi < 4; mi++){
        int row = wr + mi*16 + c;
        af[mi] = *(const bf16x8*)&Alds[row*64 + (((ks*4 + g) ^ (row & 7))*8)];
      }
      #pragma unroll
      for (int nj = 0; nj < 2; nj++){
        int row = wc + nj*16 + c;
        bfr[nj] = *(const bf16x8*)&Blds[row*64 + (((ks*4 + g) ^ (row & 7))*8)];
      }
      #pragma unroll
      for (int mi = 0; mi < 4; mi++)
        #pragma unroll
        for (int nj = 0; nj < 2; nj++)
          acc[mi][nj] = mfma16(af[mi], bfr[nj], acc[mi][nj]);
    }
  }

  if (z == 2){
    // V: transposed write, rows 4g+r consecutive -> ushort4 stores
    #pragma unroll
    for (int mi = 0; mi < 4; mi++){
      int row0 = mbase + wr + mi*16 + 4*g;
      int bb = row0 >> 11, s0 = row0 & (SEQ-1);
      #pragma unroll
      for (int nj = 0; nj < 2; nj++){
        int col = nbase + wc + nj*16 + c;
        int hh = col >> 6, d = col & 63;
        ushort4 v;
        v.x = cvt1(acc[mi][nj][0]); v.y = cvt1(acc[mi][nj][1]);
        v.z = cvt1(acc[mi][nj][2]); v.w = cvt1(acc[mi][nj][3]);
        *(ushort4*)&Vt[((long)(bb*NH + hh)*HD + d)*SEQ + s0] = v;
      }
    }
  } else {
    u16* Out = (z == 0) ? Qd : Kd;
    const float scale = (z == 0) ? 0.125f*1.44269504089f : 1.f;  // SC folded into Q
    const bool even = (c & 1) == 0;
    #pragma unroll
    for (int mi = 0; mi < 4; mi++){
      #pragma unroll
      for (int r = 0; r < 4; r++){
        int row = mbase + wr + mi*16 + 4*g + r;
        int bb = row >> 11, s = row & (SEQ-1);
        int p = pos[bb*SEQ + s];
        if (p < 0) p = 0; if (p >= SEQ) p = SEQ - 1;
        #pragma unroll
        for (int nj = 0; nj < 2; nj++){
          int col = nbase + wc + nj*16 + c;
          float2 cs = tab[p*32 + ((col & 63) >> 1)];
          float own = acc[mi][nj][r];
          float prt = __shfl_xor(own, 1);
          float rr = even ? (own*cs.x - prt*cs.y) : (prt*cs.y + own*cs.x);
          rr *= scale;
          Out[(long)row*DM + col] = cvt1(rr);   // natural layout, coalesced
        }
      }
    }
  }
}

// ---------------- gemm_out: 128x64 tile, 1D grid 512 XCD-swizzled ----------------
__global__ __launch_bounds__(256) void gemm_out(const u16* __restrict__ Zb,
                                                const u16* __restrict__ wob,
                                                float* __restrict__ out)
{
  __shared__ u16 Alds[128*64];
  __shared__ u16 Blds[64*64];
  const int fid = blockIdx.x;
  const int xj = fid & 7, tt = fid >> 3;          // 0..63
  const int mb = (tt/16)*8 + xj;                  // 0..31
  const int nb = tt % 16;                         // 0..15
  const int nbase = nb*64, mbase = mb*128;
  const int tid = threadIdx.x;
  const int w = tid >> 6, l = tid & 63, g = l >> 4, c = l & 15;
  const int wr = (w >> 1)*64, wc = (w & 1)*32;
  const int srow = l >> 3;
  const int scol = ((l & 7) ^ srow)*8;
  const u16* Ag = Zb  + (long)(mbase + w*32 + srow)*DM + scol;
  const u16* Bg = wob + (long)(nbase + w*16 + srow)*DM + scol;
  u16* Alb = Alds + w*2048;
  u16* Blb = Blds + w*1024;
  f32x4 acc[4][2] = {};

  for (int k0 = 0; k0 < DM; k0 += 64){
    __syncthreads();
    #pragma unroll
    for (int i = 0; i < 4; i++)
      gload_lds16(Ag + k0 + (long)(8*i)*DM, Alb + i*512);
    #pragma unroll
    for (int i = 0; i < 2; i++)
      gload_lds16(Bg + k0 + (long)(8*i)*DM, Blb + i*512);
    __syncthreads();
    #pragma unroll
    for (int ks = 0; ks < 2; ks++){
      bf16x8 af[4], bfr[2];
      #pragma unroll
      for (int mi = 0; mi < 4; mi++){
        int row = wr + mi*16 + c;
        af[mi] = *(const bf16x8*)&Alds[row*64 + (((ks*4 + g) ^ (row & 7))*8)];
      }
      #pragma unroll
      for (int nj = 0; nj < 2; nj++){
        int row = wc + nj*16 + c;
        bfr[nj] = *(const bf16x8*)&Blds[row*64 + (((ks*4 + g) ^ (row & 7))*8)];
      }
      #pragma unroll
      for (int mi = 0; mi < 4; mi++)
        #pragma unroll
        for (int nj = 0; nj < 2; nj++)
          acc[mi][nj] = mfma16(af[mi], bfr[nj], acc[mi][nj]);
    }
  }
  #pragma unroll
  for (int mi = 0; mi < 4; mi++)
    #pragma unroll
    for (int nj = 0; nj < 2; nj++)
      #pragma unroll
      for (int r = 0; r < 4; r++){
        int row = mbase + wr + mi*16 + 4*g + r;
        int col = nbase + wc + nj*16 + c;
        out[(long)row*DM + col] = acc[mi][nj][r];
      }
}

// ---------------- causal flash attention: paired qtiles x KV-split ----------
// Q/K read from natural layout [b*s][e] (row stride DM, h-slice columns).
// 1D grid 1024, XCD-swizzled. R11 math, R12 addressing.
__device__ __forceinline__ int kperm(int a){
  return (a & 32) | ((a & 4) << 2) | ((a & 24) >> 1) | (a & 3);
}

__global__ __launch_bounds__(256) void attn(const u16* __restrict__ Q, const u16* __restrict__ K,
                                            const u16* __restrict__ Vt,
                                            u16* __restrict__ Opart, float* __restrict__ Lsum)
{
  const int fid = blockIdx.x;
  const int xj = fid & 7, tt = fid >> 3;          // 0..127
  const int grp = (tt >> 5)*8 + xj;               // 0..31  (h,b) group
  const int within = tt & 31;                     // 0..31
  const int h = grp & 15, b = grp >> 4;
  const int pair = within >> 1;
  const int half = within & 1;
  const int tid = threadIdx.x, w = tid >> 6, l = tid & 63, g = l >> 4, c = l & 15;
  const u16* Kp = K  + (long)(b*SEQ)*DM + h*HD;    // row stride DM
  const u16* Vp = Vt + (long)(b*NH + h)*HD*SEQ;

  __shared__ u16 KV[2][2][64][64];   // [buf][0=K,1=V][row][col]
  u16* kv = &KV[0][0][0][0];

  const int srow0 = tid >> 3, sch = tid & 7;
  const int kpr0 = kperm(srow0), kpr1 = kperm(srow0 + 32);
  const int cswz = c & 7;

  // loop-invariant LDS offsets (elements)
  const int wk0 = kpr0*64 + (sch ^ (kpr0 & 7))*8;
  const int wk1 = kpr1*64 + (sch ^ (kpr1 & 7))*8;
  const int wv0 = 4096 + srow0*64 + (sch ^ (srow0 & 7))*8;
  const int wv1 = 4096 + (srow0 + 32)*64 + (sch ^ ((srow0 + 32) & 7))*8;
  const int ra0 = c*64 + (((0 + g) ^ cswz)*8);
  const int ra1 = c*64 + (((4 + g) ^ cswz)*8);

  bf16x8 ones;
  #pragma unroll
  for (int j = 0; j < 8; j++) ones[j] = (short)0x3F80;   // bf16 1.0

  int bufo = 0;                      // element offset of current buffer (0 / 8192)
  #pragma unroll 1
  for (int seg = 0; seg < 2; ++seg){
    const int qt = seg ? (31 - pair) : pair;
    const int qbase = qt*64;
    const int qrow = qbase + w*16;
    const u16* Qp = Q + (long)(b*SEQ + qrow)*DM + h*HD;   // row stride DM
    bf16x8 qf0 = *(const bf16x8*)(Qp + c*DM + g*8);
    bf16x8 qf1 = *(const bf16x8*)(Qp + c*DM + 32 + g*8);

    const int ntH0  = (qt + 2) >> 1;            // ceil((qt+1)/2)
    const int tstart = half ? ntH0 : 0;
    const int tend   = half ? (qt + 1) : ntH0;

    f32x4 accz[4] = {};
    f32x4 lacc = {};                            // row-sums, acc layout (q=4g+r)

    if (tstart < tend){
      __syncthreads();   // previous segment's LDS reads complete
      const u16* kg0 = Kp + (long)(tstart*64 + srow0)*DM + sch*8;
      const u16* kg1 = kg0 + (long)32*DM;
      const u16* vg0 = Vp + (long)srow0*SEQ + tstart*64 + sch*8;
      const u16* vg1 = vg0 + 32*SEQ;
      bf16x8 kr0 = *(const bf16x8*)kg0, kr1 = *(const bf16x8*)kg1;
      bf16x8 vr0 = *(const bf16x8*)vg0, vr1 = *(const bf16x8*)vg1;
      kg0 += (long)64*DM; kg1 += (long)64*DM; vg0 += 64; vg1 += 64;
      *(bf16x8*)(kv + bufo + wk0) = kr0;
      *(bf16x8*)(kv + bufo + wk1) = kr1;
      *(bf16x8*)(kv + bufo + wv0) = vr0;
      *(bf16x8*)(kv + bufo + wv1) = vr1;

      for (int t = tstart; t < tend; ++t){
        const int kbase = t*64;
        __syncthreads();   // buf ready; all prior reads of other buf done

        if (t < tend-1){   // T14: issue next tile's global loads now, write LDS later
          kr0 = *(const bf16x8*)kg0; kr1 = *(const bf16x8*)kg1;
          vr0 = *(const bf16x8*)vg0; vr1 = *(const bf16x8*)vg1;
          kg0 += (long)64*DM; kg1 += (long)64*DM; vg0 += 64; vg1 += 64;
        }

        const u16* kvb = kv + bufo;

        // QK^T (swapped): s[sub][r] = S_stored[sub*16+4g+r][q=c], pre-scaled
        f32x4 s[4];
        __builtin_amdgcn_s_setprio(1);
        #pragma unroll
        for (int sub = 0; sub < 4; sub++){
          bf16x8 ka0 = *(const bf16x8*)(kvb + ra0 + sub*1024);
          bf16x8 ka1 = *(const bf16x8*)(kvb + ra1 + sub*1024);
          f32x4 z4 = {};
          z4 = mfma16(ka0, qf0, z4);
          z4 = mfma16(ka1, qf1, z4);
          s[sub] = z4;
        }
        __builtin_amdgcn_s_setprio(0);

        // causal mask; then P = exp2(s) directly (drop-max: inputs bounded)
        const bool edge = (kbase + 63 > qrow);
        const int q = qrow + c;
        if (edge){
          #pragma unroll
          for (int sub = 0; sub < 4; sub++)
            #pragma unroll
            for (int r = 0; r < 4; r++){
              int key = kbase + ((sub >> 1) << 5) + 8*g + ((sub & 1) << 2) + r;
              if (key > q) s[sub][r] = -1e30f;
            }
        }
        #pragma unroll
        for (int sub = 0; sub < 4; sub++)
          #pragma unroll
          for (int r = 0; r < 4; r++)
            s[sub][r] = exp2f(s[sub][r]);

        // P -> bf16 A-frags, fully in-lane (keys 8g..8g+7 and 32+8g..+7)
        u32x4 p0, p1;
        p0[0] = pk2(s[0][0], s[0][1]); p0[1] = pk2(s[0][2], s[0][3]);
        p0[2] = pk2(s[1][0], s[1][1]); p0[3] = pk2(s[1][2], s[1][3]);
        p1[0] = pk2(s[2][0], s[2][1]); p1[1] = pk2(s[2][2], s[2][3]);
        p1[2] = pk2(s[3][0], s[3][1]); p1[3] = pk2(s[3][2], s[3][3]);
        bf16x8 pf0 = __builtin_bit_cast(bf16x8, p0);
        bf16x8 pf1 = __builtin_bit_cast(bf16x8, p1);

        // PV + row-sum (ones-MFMA): lacc[r] += sum_k P[q=4g+r][k]
        __builtin_amdgcn_s_setprio(1);
        lacc = mfma16(pf0, ones, lacc);
        lacc = mfma16(pf1, ones, lacc);
        #pragma unroll
        for (int dt = 0; dt < 4; dt++){
          bf16x8 vf0 = *(const bf16x8*)(kvb + 4096 + ra0 + dt*1024);
          bf16x8 vf1 = *(const bf16x8*)(kvb + 4096 + ra1 + dt*1024);
          accz[dt] = mfma16(pf0, vf0, accz[dt]);
          accz[dt] = mfma16(pf1, vf1, accz[dt]);
        }
        __builtin_amdgcn_s_setprio(0);

        if (t < tend-1){   // write next tile into the other buffer (no barrier needed)
          int nbo = bufo ^ 8192;
          *(bf16x8*)(kv + nbo + wk0) = kr0;
          *(bf16x8*)(kv + nbo + wk1) = kr1;
          *(bf16x8*)(kv + nbo + wv0) = vr0;
          *(bf16x8*)(kv + nbo + wv1) = vr1;
          bufo = nbo;
        }
      }
    }

    // write partials: unnormalized O (bf16) + lsum per row (q = 4g+r)
    const int pbase = (((b*NH + h)*32 + qt)*2 + half);
    if (c == 0){
      #pragma unroll
      for (int r = 0; r < 4; r++)
        Lsum[pbase*64 + w*16 + 4*g + r] = lacc[r];
    }
    u16* Op = Opart + (long)pbase*(64*64);
    #pragma unroll
    for (int dt = 0; dt < 4; dt++)
      #pragma unroll
      for (int r = 0; r < 4; r++)
        Op[(w*16 + 4*g + r)*64 + dt*16 + c] = cvt1(accz[dt][r]);
  }
}

// ---------------- combine the two KV-halves (no max shift needed) ----------
__global__ __launch_bounds__(256) void attn_combine(const u16* __restrict__ Opart,
                                                    const float* __restrict__ Lsum,
                                                    u16* __restrict__ Z)
{
  const int qt = blockIdx.x, h = blockIdx.y, b = blockIdx.z;   // qt 0..31
  const int p0 = ((b*NH + h)*32 + qt)*2, p1 = p0 + 1;
  const int row = threadIdx.x >> 2;          // 0..63
  const int d0  = (threadIdx.x & 3)*16;
  float inv = 1.f / (Lsum[p0*64 + row] + Lsum[p1*64 + row]);
  const u16* o0 = Opart + ((long)p0*64 + row)*64 + d0;
  const u16* o1 = Opart + ((long)p1*64 + row)*64 + d0;
  const int s = qt*64 + row;
  u16* zp = Z + (long)(b*SEQ + s)*DM + h*HD + d0;
  #pragma unroll
  for (int j = 0; j < 2; j++){
    bf16x8 va = *(const bf16x8*)(o0 + j*8);
    bf16x8 vb = *(const bf16x8*)(o1 + j*8);
    bf16x8 ov;
    #pragma unroll
    for (int e = 0; e < 8; e++){
      float z = (b2f((u16)va[e]) + b2f((u16)vb[e]))*inv;
      ov[e] = (short)cvt1(z);
    }
    *(bf16x8*)(zp + j*8) = ov;
  }
}

extern "C" void kernel_launch(void* const* d_in, const int* in_sizes, int n_in,
                              void* d_out, int out_size, void* d_ws, size_t ws_size,
                              hipStream_t stream)
{
  const float* x  = (const float*)d_in[0];
  const int*   pos= (const int*)d_in[1];
  const float* wq = (const float*)d_in[2];
  const float* wk = (const float*)d_in[3];
  const float* wv = (const float*)d_in[4];
  const float* wo = (const float*)d_in[5];
  float* out = (float*)d_out;

  const long NX = (long)MTOT*DM;
  const long NW = (long)DM*DM;
  char* p = (char*)d_ws;
  u16* xb   = (u16*)p;  p += NX*2;
  u16* wb   = (u16*)p;  p += 4*NW*2;
  u16* Qd   = (u16*)p;  p += NX*2;
  u16* Kd   = (u16*)p;  p += NX*2;
  u16* Vt   = (u16*)p;  p += NX*2;
  u16* Zb   = (u16*)p;  p += NX*2;
  float2* tab = (float2*)p; p += (long)SEQ*32*sizeof(float2);
  u16* Opart = (u16*)p;  p += 2L*NX*2;                 // 2048 chunks x 64x64 bf16
  float* Lsum = (float*)p; p += 2048L*64*sizeof(float);
  (void)ws_size; (void)n_in; (void)in_sizes; (void)out_size;

  hipLaunchKernelGGL(cvt_all,     dim3(2048),      dim3(256), 0, stream, x, wq, wk, wv, wo, xb, wb);
  hipLaunchKernelGGL(rope_table,  dim3(256),       dim3(256), 0, stream, tab);
  hipLaunchKernelGGL(gemm_qkv,    dim3(1536),      dim3(256), 0, stream, xb, wb, Qd, Kd, Vt, tab, pos);
  hipLaunchKernelGGL(attn,        dim3(1024),      dim3(256), 0, stream, Qd, Kd, Vt, Opart, Lsum);
  hipLaunchKernelGGL(attn_combine,dim3(32,16,2),   dim3(256), 0, stream, Opart, Lsum, Zb);
  hipLaunchKernelGGL(gemm_out,    dim3(512),       dim3(256), 0, stream, Zb, wb + 3*NW, out);
}